// Round 4
// baseline (1205.514 us; speedup 1.0000x reference)
//
#include <hip/hip_runtime.h>
#include <hip/hip_bf16.h>

#define N_NODES   50000
#define N_EDGES   800000
#define IN_DIM    128
#define EDGE_DIM  32
#define HIDDEN    128
#define NUM_LAYERS 3
#define BN_EPS    1e-5f
#define RES_SCALE 0.1f

typedef unsigned int   u32;
typedef unsigned short u16;
typedef _Float16 half2_t __attribute__((ext_vector_type(2)));
typedef unsigned int u32x4 __attribute__((ext_vector_type(4)));
typedef float f32x4 __attribute__((ext_vector_type(4)));

#define AS4 __attribute__((address_space(4)))

__device__ __forceinline__ half2_t as_half2(u32 v) {
    union { u32 u; half2_t h; } c; c.u = v; return c.h;
}
__device__ __forceinline__ u32 pack_half2(float a, float b) {
    union { u32 u; half2_t h; } c;
    c.h.x = (_Float16)a; c.h.y = (_Float16)b; return c.u;
}

#if defined(__has_builtin)
#if __has_builtin(__builtin_amdgcn_fdot2)
#define HAVE_FDOT2 1
#endif
#endif

__device__ __forceinline__ float fdot2f(half2_t a, half2_t b, float c) {
#ifdef HAVE_FDOT2
    return __builtin_amdgcn_fdot2(a, b, c, false);
#else
    c = fmaf((float)a.x, (float)b.x, c);
    c = fmaf((float)a.y, (float)b.y, c);
    return c;
#endif
}

// ---------------- pack x -> h16 ; zero deg ----------------
__global__ __launch_bounds__(256) void init_kernel(const float* __restrict__ x,
                                                   u32* __restrict__ h16,
                                                   u32* __restrict__ deg) {
    int idx = blockIdx.x * 256 + threadIdx.x;
    if (idx < N_NODES * 64) {
        int n = idx >> 6, l = idx & 63;
        float a = x[n * HIDDEN + l];
        float b = x[n * HIDDEN + 64 + l];
        h16[idx] = pack_half2(a, b);
    }
    if (idx < N_NODES) deg[idx] = 0u;
}

// ---------------- degree histogram ----------------
__global__ __launch_bounds__(256) void hist_kernel(const int* __restrict__ ei,
                                                   u32* __restrict__ deg) {
    int e = blockIdx.x * 256 + threadIdx.x;
    if (e < N_EDGES) atomicAdd(&deg[ei[N_EDGES + e]], 1u);
}

// ---------------- multi-block exclusive scan (3 passes) ----------------
#define SCAN_NB ((N_NODES + 255) / 256)   // 196

__global__ __launch_bounds__(256) void scan1_kernel(const u32* __restrict__ deg,
                                                    u32* __restrict__ bsum) {
    int i = blockIdx.x * 256 + threadIdx.x;
    u32 v = (i < N_NODES) ? deg[i] : 0u;
    v += __shfl_down(v, 32, 64);
    v += __shfl_down(v, 16, 64);
    v += __shfl_down(v, 8, 64);
    v += __shfl_down(v, 4, 64);
    v += __shfl_down(v, 2, 64);
    v += __shfl_down(v, 1, 64);
    __shared__ u32 ws[4];
    if ((threadIdx.x & 63) == 0) ws[threadIdx.x >> 6] = v;
    __syncthreads();
    if (threadIdx.x == 0) bsum[blockIdx.x] = ws[0] + ws[1] + ws[2] + ws[3];
}

__global__ __launch_bounds__(256) void scan2_kernel(const u32* __restrict__ bsum,
                                                    u32* __restrict__ bbase,
                                                    u32* __restrict__ off) {
    __shared__ u32 tmp[256];
    int t = threadIdx.x;
    u32 v = (t < SCAN_NB) ? bsum[t] : 0u;
    tmp[t] = v;
    __syncthreads();
    for (int d = 1; d < 256; d <<= 1) {
        u32 u = (t >= d) ? tmp[t - d] : 0u;
        __syncthreads();
        tmp[t] += u;
        __syncthreads();
    }
    if (t < SCAN_NB) bbase[t] = (t == 0) ? 0u : tmp[t - 1];
    if (t == 255) off[N_NODES] = tmp[255];   // grand total
}

__global__ __launch_bounds__(256) void scan3_kernel(const u32* __restrict__ deg,
                                                    const u32* __restrict__ bbase,
                                                    u32* __restrict__ off,
                                                    u32* __restrict__ cursor) {
    __shared__ u32 tmp[256];
    int t = threadIdx.x;
    int i = blockIdx.x * 256 + t;
    u32 v = (i < N_NODES) ? deg[i] : 0u;
    tmp[t] = v;
    __syncthreads();
    for (int d = 1; d < 256; d <<= 1) {
        u32 u = (t >= d) ? tmp[t - d] : 0u;
        __syncthreads();
        tmp[t] += u;
        __syncthreads();
    }
    if (i < N_NODES) {
        u32 excl = bbase[blockIdx.x] + tmp[t] - v;
        off[i] = excl;
        cursor[i] = excl;
    }
}

// ---------------- scatter edges into CSR order + permute ea (f16) ----------------
__global__ __launch_bounds__(256) void scatter_kernel(const int* __restrict__ ei,
                                                      u32* __restrict__ cursor,
                                                      int* __restrict__ ssrc,
                                                      const float* __restrict__ ea,
                                                      _Float16* __restrict__ ea_perm) {
    int e = blockIdx.x * 256 + threadIdx.x;
    if (e >= N_EDGES) return;
    int dst = ei[N_EDGES + e];
    u32 pos = atomicAdd(&cursor[dst], 1u);
    ssrc[pos] = ei[e];
    const float4* src = (const float4*)(ea + (size_t)e * EDGE_DIM);
    u32 buf[16];
#pragma unroll
    for (int q = 0; q < 8; q++) {
        float4 v = src[q];
        buf[2 * q + 0] = pack_half2(v.x, v.y);
        buf[2 * q + 1] = pack_half2(v.z, v.w);
    }
    uint4* dp = (uint4*)(ea_perm + (size_t)pos * EDGE_DIM);
#pragma unroll
    for (int q = 0; q < 4; q++)
        dp[q] = make_uint4(buf[4 * q], buf[4 * q + 1], buf[4 * q + 2], buf[4 * q + 3]);
}

// dot of one ea row (4 x u32x4 in SGPRs = 32 halves) against wlo/whi
__device__ __forceinline__ void edot4(const u32x4* __restrict__ d,
                                      const half2_t* __restrict__ wlo,
                                      const half2_t* __restrict__ whi,
                                      float& dl, float& dh) {
#pragma unroll
    for (int q = 0; q < 4; q++) {
        u32x4 v = d[q];
        dl = fdot2f(as_half2(v.x), wlo[q * 4 + 0], dl);
        dh = fdot2f(as_half2(v.x), whi[q * 4 + 0], dh);
        dl = fdot2f(as_half2(v.y), wlo[q * 4 + 1], dl);
        dh = fdot2f(as_half2(v.y), whi[q * 4 + 1], dh);
        dl = fdot2f(as_half2(v.z), wlo[q * 4 + 2], dl);
        dh = fdot2f(as_half2(v.z), whi[q * 4 + 2], dh);
        dl = fdot2f(as_half2(v.w), wlo[q * 4 + 3], dl);
        dh = fdot2f(as_half2(v.w), whi[q * 4 + 3], dh);
    }
}

// ---------------- CSR aggregation: one WAVE per node slot ----------------
__global__ __launch_bounds__(256) void agg_perm_kernel(
    const u32* __restrict__ h16, const _Float16* __restrict__ ea_perm,
    const int* __restrict__ ssrc, const u32* __restrict__ off,
    const float* __restrict__ We, const float* __restrict__ be,
    float* __restrict__ z) {
    int t = threadIdx.x;
    int lane = t & 63;
    half2_t wlo[16], whi[16];
#pragma unroll
    for (int k = 0; k < 16; k++) {
        half2_t a, b;
        a.x = (_Float16)We[(2 * k + 0) * HIDDEN + lane];
        a.y = (_Float16)We[(2 * k + 1) * HIDDEN + lane];
        b.x = (_Float16)We[(2 * k + 0) * HIDDEN + 64 + lane];
        b.y = (_Float16)We[(2 * k + 1) * HIDDEN + 64 + lane];
        wlo[k] = a; whi[k] = b;
    }
    float blo = be[lane], bhi = be[64 + lane];

    const AS4 int*   cssrc = (const AS4 int*)(unsigned long long)ssrc;
    const AS4 u32*   coff  = (const AS4 u32*)(unsigned long long)off;
    const AS4 u32x4* cea   = (const AS4 u32x4*)(unsigned long long)ea_perm; // 4 x u32x4 per edge

    int wid = __builtin_amdgcn_readfirstlane(t >> 6);
    int slot = blockIdx.x * 4 + wid;
    int nslots = gridDim.x * 4;
    for (int n = slot; n < N_NODES; n += nslots) {
        int e0 = (int)coff[n], e1 = (int)coff[n + 1];
        float al0 = 0.f, ah0 = 0.f, al1 = 0.f, ah1 = 0.f;
        int e = e0;
        if (e + 2 <= e1) {
            int s0 = cssrc[e], s1 = cssrc[e + 1];
            u32x4 A0[4], A1[4];
#pragma unroll
            for (int q = 0; q < 4; q++) { A0[q] = cea[e * 4 + q]; A1[q] = cea[e * 4 + 4 + q]; }
            while (true) {
                u32 g0 = h16[s0 * 64 + lane];
                u32 g1 = h16[s1 * 64 + lane];
                int en = e + 2;
                int more = (en + 2 <= e1);
                float d0l = 0.f, d0h = 0.f, d1l = 0.f, d1h = 0.f;
                edot4(A0, wlo, whi, d0l, d0h);
                edot4(A1, wlo, whi, d1l, d1h);
                int ns0 = s0, ns1 = s1;
                if (more) {
                    ns0 = cssrc[en]; ns1 = cssrc[en + 1];
#pragma unroll
                    for (int q = 0; q < 4; q++) { A0[q] = cea[en * 4 + q]; A1[q] = cea[en * 4 + 4 + q]; }
                }
                half2_t hh0 = as_half2(g0), hh1 = as_half2(g1);
                al0 += fmaxf(d0l + blo + (float)hh0.x, 0.f);
                ah0 += fmaxf(d0h + bhi + (float)hh0.y, 0.f);
                al1 += fmaxf(d1l + blo + (float)hh1.x, 0.f);
                ah1 += fmaxf(d1h + bhi + (float)hh1.y, 0.f);
                e = en;
                if (!more) break;
                s0 = ns0; s1 = ns1;
            }
        }
        if (e < e1) {  // tail: one edge
            int s0 = cssrc[e];
            u32x4 A0[4];
#pragma unroll
            for (int q = 0; q < 4; q++) A0[q] = cea[e * 4 + q];
            float dl = 0.f, dh = 0.f;
            edot4(A0, wlo, whi, dl, dh);
            half2_t hh = as_half2(h16[s0 * 64 + lane]);
            al0 += fmaxf(dl + blo + (float)hh.x, 0.f);
            ah0 += fmaxf(dh + bhi + (float)hh.y, 0.f);
        }
        half2_t self = as_half2(h16[n * 64 + lane]);
        z[n * HIDDEN + lane]      = (float)self.x + al0 + al1;
        z[n * HIDDEN + 64 + lane] = (float)self.y + ah0 + ah1;
    }
}

// ---------------- zero stats ----------------
__global__ __launch_bounds__(256) void zero_stats_kernel(float* __restrict__ stats) {
    stats[threadIdx.x] = 0.f;
}

// ---------------- fused MLP: thread-per-node, W streamed via SGPR ----------------
// z2 = relu(z @ W1 + b1) @ W2 + b2, all fp32.
// Each thread owns one node row: z in 128 VGPRs; every W[k][f] operand is
// wave-uniform -> scalar loads (AS4), SGPR src in v_fmac. Zero LDS for
// operands; h1 parked in LDS with XOR-swizzled 16B chunks (bank-floor reads).
__global__ __launch_bounds__(64) void fused_mlp_kernel(
    const float* __restrict__ zin,
    const float* __restrict__ W1_, const float* __restrict__ b1_,
    const float* __restrict__ W2_, const float* __restrict__ b2_,
    float* __restrict__ z2) {
    __shared__ float h1s[64 * HIDDEN];   // 32 KB, one row (512B) per thread
    int t = threadIdx.x;                 // 0..63, one wave per block
    int n = blockIdx.x * 64 + t;
    if (n >= N_NODES) return;

    const AS4 f32x4* cW1 = (const AS4 f32x4*)(unsigned long long)W1_;
    const AS4 f32x4* cW2 = (const AS4 f32x4*)(unsigned long long)W2_;
    const AS4 f32x4* cB1 = (const AS4 f32x4*)(unsigned long long)b1_;
    const AS4 f32x4* cB2 = (const AS4 f32x4*)(unsigned long long)b2_;

    // load own z row: 32 x dwordx4 (uncoalesced but L2/L3-resident, pipelined)
    f32x4 zr[32];
    const f32x4* zp = (const f32x4*)(zin + (size_t)n * HIDDEN);
#pragma unroll
    for (int c = 0; c < 32; c++) zr[c] = zp[c];

    int sw = t & 31;                         // swizzle key
    char* hrow = (char*)h1s + t * 512;       // own LDS row base (bytes)

    // ---- GEMM1: h1 = relu(z @ W1 + b1), 8 features per fc iteration ----
#pragma unroll 1
    for (int fc = 0; fc < 16; fc++) {
        f32x4 bb0 = cB1[fc * 2], bb1 = cB1[fc * 2 + 1];
        float acc[8] = {bb0.x, bb0.y, bb0.z, bb0.w, bb1.x, bb1.y, bb1.z, bb1.w};
#pragma unroll
        for (int c = 0; c < 32; c++) {
#pragma unroll
            for (int kk = 0; kk < 4; kk++) {
                int k = c * 4 + kk;
                f32x4 w0 = cW1[k * 32 + fc * 2];
                f32x4 w1 = cW1[k * 32 + fc * 2 + 1];
                float zv = zr[c][kk];
                acc[0] = fmaf(zv, w0.x, acc[0]);
                acc[1] = fmaf(zv, w0.y, acc[1]);
                acc[2] = fmaf(zv, w0.z, acc[2]);
                acc[3] = fmaf(zv, w0.w, acc[3]);
                acc[4] = fmaf(zv, w1.x, acc[4]);
                acc[5] = fmaf(zv, w1.y, acc[5]);
                acc[6] = fmaf(zv, w1.z, acc[6]);
                acc[7] = fmaf(zv, w1.w, acc[7]);
            }
        }
        f32x4 r0, r1;
        r0.x = fmaxf(acc[0], 0.f); r0.y = fmaxf(acc[1], 0.f);
        r0.z = fmaxf(acc[2], 0.f); r0.w = fmaxf(acc[3], 0.f);
        r1.x = fmaxf(acc[4], 0.f); r1.y = fmaxf(acc[5], 0.f);
        r1.z = fmaxf(acc[6], 0.f); r1.w = fmaxf(acc[7], 0.f);
        int c0 = (2 * fc) ^ sw, c1 = (2 * fc + 1) ^ sw;
        *(f32x4*)(hrow + c0 * 16) = r0;
        *(f32x4*)(hrow + c1 * 16) = r1;
    }

    // ---- GEMM2: z2 = h1 @ W2 + b2 ----
#pragma unroll 1
    for (int fc = 0; fc < 16; fc++) {
        f32x4 bb0 = cB2[fc * 2], bb1 = cB2[fc * 2 + 1];
        float acc[8] = {bb0.x, bb0.y, bb0.z, bb0.w, bb1.x, bb1.y, bb1.z, bb1.w};
#pragma unroll
        for (int c = 0; c < 32; c++) {
            f32x4 h = *(const f32x4*)(hrow + ((c ^ sw) * 16));
#pragma unroll
            for (int kk = 0; kk < 4; kk++) {
                int k = c * 4 + kk;
                f32x4 w0 = cW2[k * 32 + fc * 2];
                f32x4 w1 = cW2[k * 32 + fc * 2 + 1];
                float hv = h[kk];
                acc[0] = fmaf(hv, w0.x, acc[0]);
                acc[1] = fmaf(hv, w0.y, acc[1]);
                acc[2] = fmaf(hv, w0.z, acc[2]);
                acc[3] = fmaf(hv, w0.w, acc[3]);
                acc[4] = fmaf(hv, w1.x, acc[4]);
                acc[5] = fmaf(hv, w1.y, acc[5]);
                acc[6] = fmaf(hv, w1.z, acc[6]);
                acc[7] = fmaf(hv, w1.w, acc[7]);
            }
        }
        float* op = z2 + (size_t)n * HIDDEN + fc * 8;
        *(float4*)op       = make_float4(acc[0], acc[1], acc[2], acc[3]);
        *(float4*)(op + 4) = make_float4(acc[4], acc[5], acc[6], acc[7]);
    }
}

// ---------------- per-feature stats (sum, sumsq) over nodes ----------------
#define STATS_NB 256
__global__ __launch_bounds__(256) void stats_kernel(const float* __restrict__ z2,
                                                    float* __restrict__ stats) {
    __shared__ float red[4][4][64];   // [wave][quantity][lane]
    int t = threadIdx.x, lane = t & 63, w = t >> 6;
    float sl = 0.f, sql = 0.f, sh = 0.f, sqh = 0.f;
    for (int n = blockIdx.x * 4 + w; n < N_NODES; n += STATS_NB * 4) {
        float a = z2[n * HIDDEN + lane];
        float b = z2[n * HIDDEN + 64 + lane];
        sl += a; sql = fmaf(a, a, sql);
        sh += b; sqh = fmaf(b, b, sqh);
    }
    red[w][0][lane] = sl;
    red[w][1][lane] = sql;
    red[w][2][lane] = sh;
    red[w][3][lane] = sqh;
    __syncthreads();
    if (t < 64) {
        unsafeAtomicAdd(&stats[t],
            red[0][0][t] + red[1][0][t] + red[2][0][t] + red[3][0][t]);
    } else if (t < 128) {
        int l = t - 64;
        unsafeAtomicAdd(&stats[64 + l],
            red[0][2][l] + red[1][2][l] + red[2][2][l] + red[3][2][l]);
    } else if (t < 192) {
        int l = t - 128;
        unsafeAtomicAdd(&stats[128 + l],
            red[0][1][l] + red[1][1][l] + red[2][1][l] + red[3][1][l]);
    } else {
        int l = t - 192;
        unsafeAtomicAdd(&stats[192 + l],
            red[0][3][l] + red[1][3][l] + red[2][3][l] + red[3][3][l]);
    }
}

// ---------------- batchnorm + relu + residual (paired features) ----------------
__global__ __launch_bounds__(256) void bn_kernel(
    const float* __restrict__ z2, const float* __restrict__ stats,
    const float* __restrict__ gamma, const float* __restrict__ beta,
    u32* __restrict__ h16, float* __restrict__ out, int write_out) {
    int idx = blockIdx.x * 256 + threadIdx.x;
    if (idx >= N_NODES * 64) return;
    int n = idx >> 6, l = idx & 63;
    const float inv_n = 1.0f / (float)N_NODES;
    float mu_l = stats[l] * inv_n;
    float mu_h = stats[64 + l] * inv_n;
    float var_l = stats[HIDDEN + l] * inv_n - mu_l * mu_l;
    float var_h = stats[HIDDEN + 64 + l] * inv_n - mu_h * mu_h;
    float inv_l = rsqrtf(var_l + BN_EPS);
    float inv_h = rsqrtf(var_h + BN_EPS);
    float zl = (z2[n * HIDDEN + l]      - mu_l) * inv_l * gamma[l]      + beta[l];
    float zh = (z2[n * HIDDEN + 64 + l] - mu_h) * inv_h * gamma[64 + l] + beta[64 + l];
    zl = fmaxf(zl, 0.f);
    zh = fmaxf(zh, 0.f);
    half2_t hh = as_half2(h16[idx]);
    float hn_l = fmaf(RES_SCALE, (float)hh.x, zl);
    float hn_h = fmaf(RES_SCALE, (float)hh.y, zh);
    h16[idx] = pack_half2(hn_l, hn_h);
    if (write_out) {
        out[n * HIDDEN + l] = hn_l;
        out[n * HIDDEN + 64 + l] = hn_h;
    }
}

extern "C" void kernel_launch(void* const* d_in, const int* in_sizes, int n_in,
                              void* d_out, int out_size, void* d_ws, size_t ws_size,
                              hipStream_t stream) {
    const float* x     = (const float*)d_in[0];
    const int*   ei    = (const int*)d_in[1];
    const float* ea    = (const float*)d_in[2];
    const float* We    = (const float*)d_in[3];
    const float* be    = (const float*)d_in[4];
    const float* W1    = (const float*)d_in[5];
    const float* b1    = (const float*)d_in[6];
    const float* W2    = (const float*)d_in[7];
    const float* b2    = (const float*)d_in[8];
    const float* gamma = (const float*)d_in[9];
    const float* beta  = (const float*)d_in[10];
    float* out = (float*)d_out;

    char* wsp = (char*)d_ws;
    const size_t NH = (size_t)N_NODES * HIDDEN;
    u32*      h16    = (u32*)wsp;      wsp += (size_t)N_NODES * 64 * 4;        // 12.8 MB
    float*    z      = (float*)wsp;    wsp += NH * 4;                          // 25.6 MB
    _Float16* ea_perm= (_Float16*)wsp; wsp += (size_t)N_EDGES * EDGE_DIM * 2;  // 51.2 MB
    float*    stats  = (float*)wsp;    wsp += 256 * 4;
    u32*      deg    = (u32*)wsp;      wsp += (size_t)N_NODES * 4;
    u32*      cursor = (u32*)wsp;      wsp += (size_t)N_NODES * 4;
    int*      ssrc   = (int*)wsp;      wsp += (size_t)N_EDGES * 4;
    u32*      off    = (u32*)wsp;      wsp += (size_t)(N_NODES + 1) * 4;
    u32*      bsum   = (u32*)wsp;      wsp += (size_t)SCAN_NB * 4;
    u32*      bbase  = (u32*)wsp;      wsp += (size_t)SCAN_NB * 4;

    const int p_blocks  = (N_NODES * 64 + 255) / 256;       // 12500
    const int e_blocks  = (N_EDGES + 255) / 256;            // 3125
    const int m_blocks  = (N_NODES + 63) / 64;              // 782

    // CSR build (once per call)
    init_kernel<<<p_blocks, 256, 0, stream>>>(x, h16, deg);
    hist_kernel<<<e_blocks, 256, 0, stream>>>(ei, deg);
    scan1_kernel<<<SCAN_NB, 256, 0, stream>>>(deg, bsum);
    scan2_kernel<<<1, 256, 0, stream>>>(bsum, bbase, off);
    scan3_kernel<<<SCAN_NB, 256, 0, stream>>>(deg, bbase, off, cursor);
    scatter_kernel<<<e_blocks, 256, 0, stream>>>(ei, cursor, ssrc, ea, ea_perm);

    for (int l = 0; l < NUM_LAYERS; l++) {
        agg_perm_kernel<<<4096, 256, 0, stream>>>(
            h16, ea_perm, ssrc, off,
            We + (size_t)l * EDGE_DIM * HIDDEN, be + (size_t)l * HIDDEN, z);
        fused_mlp_kernel<<<m_blocks, 64, 0, stream>>>(
            z, W1 + (size_t)l * HIDDEN * HIDDEN, b1 + (size_t)l * HIDDEN,
            W2 + (size_t)l * HIDDEN * HIDDEN, b2 + (size_t)l * HIDDEN, z);
        zero_stats_kernel<<<1, 256, 0, stream>>>(stats);
        stats_kernel<<<STATS_NB, 256, 0, stream>>>(z, stats);
        bn_kernel<<<p_blocks, 256, 0, stream>>>(
            z, stats, gamma + (size_t)l * HIDDEN, beta + (size_t)l * HIDDEN,
            h16, out, (l == NUM_LAYERS - 1) ? 1 : 0);
    }
}

// Round 5
// 815.260 us; speedup vs baseline: 1.4787x; 1.4787x over previous
//
#include <hip/hip_runtime.h>
#include <hip/hip_bf16.h>

#define N_NODES   50000
#define N_EDGES   800000
#define IN_DIM    128
#define EDGE_DIM  32
#define HIDDEN    128
#define NUM_LAYERS 3
#define BN_EPS    1e-5f
#define RES_SCALE 0.1f

typedef unsigned int   u32;
typedef unsigned short u16;
typedef _Float16 half2_t __attribute__((ext_vector_type(2)));
typedef unsigned int u32x4 __attribute__((ext_vector_type(4)));
typedef float f32x4 __attribute__((ext_vector_type(4)));

#define AS4 __attribute__((address_space(4)))

__device__ __forceinline__ half2_t as_half2(u32 v) {
    union { u32 u; half2_t h; } c; c.u = v; return c.h;
}
__device__ __forceinline__ u32 pack_half2(float a, float b) {
    union { u32 u; half2_t h; } c;
    c.h.x = (_Float16)a; c.h.y = (_Float16)b; return c.u;
}

#if defined(__has_builtin)
#if __has_builtin(__builtin_amdgcn_fdot2)
#define HAVE_FDOT2 1
#endif
#endif

__device__ __forceinline__ float fdot2f(half2_t a, half2_t b, float c) {
#ifdef HAVE_FDOT2
    return __builtin_amdgcn_fdot2(a, b, c, false);
#else
    c = fmaf((float)a.x, (float)b.x, c);
    c = fmaf((float)a.y, (float)b.y, c);
    return c;
#endif
}

// ---------------- pack x -> h16 ; zero deg ----------------
__global__ __launch_bounds__(256) void init_kernel(const float* __restrict__ x,
                                                   u32* __restrict__ h16,
                                                   u32* __restrict__ deg) {
    int idx = blockIdx.x * 256 + threadIdx.x;
    if (idx < N_NODES * 64) {
        int n = idx >> 6, l = idx & 63;
        float a = x[n * HIDDEN + l];
        float b = x[n * HIDDEN + 64 + l];
        h16[idx] = pack_half2(a, b);
    }
    if (idx < N_NODES) deg[idx] = 0u;
}

// ---------------- degree histogram ----------------
__global__ __launch_bounds__(256) void hist_kernel(const int* __restrict__ ei,
                                                   u32* __restrict__ deg) {
    int e = blockIdx.x * 256 + threadIdx.x;
    if (e < N_EDGES) atomicAdd(&deg[ei[N_EDGES + e]], 1u);
}

// ---------------- multi-block exclusive scan (3 passes) ----------------
#define SCAN_NB ((N_NODES + 255) / 256)   // 196

__global__ __launch_bounds__(256) void scan1_kernel(const u32* __restrict__ deg,
                                                    u32* __restrict__ bsum) {
    int i = blockIdx.x * 256 + threadIdx.x;
    u32 v = (i < N_NODES) ? deg[i] : 0u;
    v += __shfl_down(v, 32, 64);
    v += __shfl_down(v, 16, 64);
    v += __shfl_down(v, 8, 64);
    v += __shfl_down(v, 4, 64);
    v += __shfl_down(v, 2, 64);
    v += __shfl_down(v, 1, 64);
    __shared__ u32 ws[4];
    if ((threadIdx.x & 63) == 0) ws[threadIdx.x >> 6] = v;
    __syncthreads();
    if (threadIdx.x == 0) bsum[blockIdx.x] = ws[0] + ws[1] + ws[2] + ws[3];
}

__global__ __launch_bounds__(256) void scan2_kernel(const u32* __restrict__ bsum,
                                                    u32* __restrict__ bbase,
                                                    u32* __restrict__ off) {
    __shared__ u32 tmp[256];
    int t = threadIdx.x;
    u32 v = (t < SCAN_NB) ? bsum[t] : 0u;
    tmp[t] = v;
    __syncthreads();
    for (int d = 1; d < 256; d <<= 1) {
        u32 u = (t >= d) ? tmp[t - d] : 0u;
        __syncthreads();
        tmp[t] += u;
        __syncthreads();
    }
    if (t < SCAN_NB) bbase[t] = (t == 0) ? 0u : tmp[t - 1];
    if (t == 255) off[N_NODES] = tmp[255];   // grand total
}

__global__ __launch_bounds__(256) void scan3_kernel(const u32* __restrict__ deg,
                                                    const u32* __restrict__ bbase,
                                                    u32* __restrict__ off,
                                                    u32* __restrict__ cursor) {
    __shared__ u32 tmp[256];
    int t = threadIdx.x;
    int i = blockIdx.x * 256 + t;
    u32 v = (i < N_NODES) ? deg[i] : 0u;
    tmp[t] = v;
    __syncthreads();
    for (int d = 1; d < 256; d <<= 1) {
        u32 u = (t >= d) ? tmp[t - d] : 0u;
        __syncthreads();
        tmp[t] += u;
        __syncthreads();
    }
    if (i < N_NODES) {
        u32 excl = bbase[blockIdx.x] + tmp[t] - v;
        off[i] = excl;
        cursor[i] = excl;
    }
}

// ---------------- scatter edges into CSR order + permute ea (f16) ----------------
__global__ __launch_bounds__(256) void scatter_kernel(const int* __restrict__ ei,
                                                      u32* __restrict__ cursor,
                                                      int* __restrict__ ssrc,
                                                      const float* __restrict__ ea,
                                                      _Float16* __restrict__ ea_perm) {
    int e = blockIdx.x * 256 + threadIdx.x;
    if (e >= N_EDGES) return;
    int dst = ei[N_EDGES + e];
    u32 pos = atomicAdd(&cursor[dst], 1u);
    ssrc[pos] = ei[e];
    const float4* src = (const float4*)(ea + (size_t)e * EDGE_DIM);
    u32 buf[16];
#pragma unroll
    for (int q = 0; q < 8; q++) {
        float4 v = src[q];
        buf[2 * q + 0] = pack_half2(v.x, v.y);
        buf[2 * q + 1] = pack_half2(v.z, v.w);
    }
    uint4* dp = (uint4*)(ea_perm + (size_t)pos * EDGE_DIM);
#pragma unroll
    for (int q = 0; q < 4; q++)
        dp[q] = make_uint4(buf[4 * q], buf[4 * q + 1], buf[4 * q + 2], buf[4 * q + 3]);
}

// dot of one ea row (4 x u32x4 in SGPRs = 32 halves) against wlo/whi
__device__ __forceinline__ void edot4(const u32x4* __restrict__ d,
                                      const half2_t* __restrict__ wlo,
                                      const half2_t* __restrict__ whi,
                                      float& dl, float& dh) {
#pragma unroll
    for (int q = 0; q < 4; q++) {
        u32x4 v = d[q];
        dl = fdot2f(as_half2(v.x), wlo[q * 4 + 0], dl);
        dh = fdot2f(as_half2(v.x), whi[q * 4 + 0], dh);
        dl = fdot2f(as_half2(v.y), wlo[q * 4 + 1], dl);
        dh = fdot2f(as_half2(v.y), whi[q * 4 + 1], dh);
        dl = fdot2f(as_half2(v.z), wlo[q * 4 + 2], dl);
        dh = fdot2f(as_half2(v.z), whi[q * 4 + 2], dh);
        dl = fdot2f(as_half2(v.w), wlo[q * 4 + 3], dl);
        dh = fdot2f(as_half2(v.w), whi[q * 4 + 3], dh);
    }
}

// ---------------- CSR aggregation: one WAVE per node slot ----------------
__global__ __launch_bounds__(256) void agg_perm_kernel(
    const u32* __restrict__ h16, const _Float16* __restrict__ ea_perm,
    const int* __restrict__ ssrc, const u32* __restrict__ off,
    const float* __restrict__ We, const float* __restrict__ be,
    float* __restrict__ z) {
    int t = threadIdx.x;
    int lane = t & 63;
    half2_t wlo[16], whi[16];
#pragma unroll
    for (int k = 0; k < 16; k++) {
        half2_t a, b;
        a.x = (_Float16)We[(2 * k + 0) * HIDDEN + lane];
        a.y = (_Float16)We[(2 * k + 1) * HIDDEN + lane];
        b.x = (_Float16)We[(2 * k + 0) * HIDDEN + 64 + lane];
        b.y = (_Float16)We[(2 * k + 1) * HIDDEN + 64 + lane];
        wlo[k] = a; whi[k] = b;
    }
    float blo = be[lane], bhi = be[64 + lane];

    const AS4 int*   cssrc = (const AS4 int*)(unsigned long long)ssrc;
    const AS4 u32*   coff  = (const AS4 u32*)(unsigned long long)off;
    const AS4 u32x4* cea   = (const AS4 u32x4*)(unsigned long long)ea_perm; // 4 x u32x4 per edge

    int wid = __builtin_amdgcn_readfirstlane(t >> 6);
    int slot = blockIdx.x * 4 + wid;
    int nslots = gridDim.x * 4;
    for (int n = slot; n < N_NODES; n += nslots) {
        int e0 = (int)coff[n], e1 = (int)coff[n + 1];
        float al0 = 0.f, ah0 = 0.f, al1 = 0.f, ah1 = 0.f;
        int e = e0;
        if (e + 2 <= e1) {
            int s0 = cssrc[e], s1 = cssrc[e + 1];
            u32x4 A0[4], A1[4];
#pragma unroll
            for (int q = 0; q < 4; q++) { A0[q] = cea[e * 4 + q]; A1[q] = cea[e * 4 + 4 + q]; }
            while (true) {
                u32 g0 = h16[s0 * 64 + lane];
                u32 g1 = h16[s1 * 64 + lane];
                int en = e + 2;
                int more = (en + 2 <= e1);
                float d0l = 0.f, d0h = 0.f, d1l = 0.f, d1h = 0.f;
                edot4(A0, wlo, whi, d0l, d0h);
                edot4(A1, wlo, whi, d1l, d1h);
                int ns0 = s0, ns1 = s1;
                if (more) {
                    ns0 = cssrc[en]; ns1 = cssrc[en + 1];
#pragma unroll
                    for (int q = 0; q < 4; q++) { A0[q] = cea[en * 4 + q]; A1[q] = cea[en * 4 + 4 + q]; }
                }
                half2_t hh0 = as_half2(g0), hh1 = as_half2(g1);
                al0 += fmaxf(d0l + blo + (float)hh0.x, 0.f);
                ah0 += fmaxf(d0h + bhi + (float)hh0.y, 0.f);
                al1 += fmaxf(d1l + blo + (float)hh1.x, 0.f);
                ah1 += fmaxf(d1h + bhi + (float)hh1.y, 0.f);
                e = en;
                if (!more) break;
                s0 = ns0; s1 = ns1;
            }
        }
        if (e < e1) {  // tail: one edge
            int s0 = cssrc[e];
            u32x4 A0[4];
#pragma unroll
            for (int q = 0; q < 4; q++) A0[q] = cea[e * 4 + q];
            float dl = 0.f, dh = 0.f;
            edot4(A0, wlo, whi, dl, dh);
            half2_t hh = as_half2(h16[s0 * 64 + lane]);
            al0 += fmaxf(dl + blo + (float)hh.x, 0.f);
            ah0 += fmaxf(dh + bhi + (float)hh.y, 0.f);
        }
        half2_t self = as_half2(h16[n * 64 + lane]);
        z[n * HIDDEN + lane]      = (float)self.x + al0 + al1;
        z[n * HIDDEN + 64 + lane] = (float)self.y + ah0 + ah1;
    }
}

// ---------------- zero stats ----------------
__global__ __launch_bounds__(256) void zero_stats_kernel(float* __restrict__ stats) {
    stats[threadIdx.x] = 0.f;
}

// ---------------- fused MLP v2: 4-wave blocks, 64 nodes, W via SGPR ----------------
// Wave w computes features [32w,32w+32) for 64 nodes (lane=node). z tile in LDS
// transposed (stride 65, conflict-free). W streamed on scalar pipe with
// prefetch-next-k. 3 waves/SIMD resident for latency hiding. h1 reuses the
// same LDS buffer between barriers; output transposes through LDS for
// coalesced stores. In-place safe (block reads only its own tile first).
__global__ __launch_bounds__(256) void fused_mlp_kernel(
    const float* __restrict__ zin,
    const float* __restrict__ W1_, const float* __restrict__ b1_,
    const float* __restrict__ W2_, const float* __restrict__ b2_,
    float* __restrict__ z2) {
    __shared__ float zT[128 * 65];       // [k][node], stride 65: 33.3 KB
    int t = threadIdx.x;
    int lane = t & 63;
    int fbq = __builtin_amdgcn_readfirstlane((t >> 6) << 3);  // fbase/4: 0,8,16,24
    int base = blockIdx.x * 64;

    // stage z tile transposed, zero-pad OOB nodes; writes stride-65 -> conflict-free
    for (int i = t; i < 64 * 128; i += 256) {
        int n = i >> 7, k = i & 127;
        int gn = base + n;
        zT[k * 65 + n] = (gn < N_NODES) ? zin[(size_t)gn * HIDDEN + k] : 0.f;
    }
    __syncthreads();

    const AS4 f32x4* cW1 = (const AS4 f32x4*)(unsigned long long)W1_;
    const AS4 f32x4* cW2 = (const AS4 f32x4*)(unsigned long long)W2_;
    const AS4 f32x4* cB1 = (const AS4 f32x4*)(unsigned long long)b1_;
    const AS4 f32x4* cB2 = (const AS4 f32x4*)(unsigned long long)b2_;

    float acc[32];

    // ---- GEMM1: h1 = relu(z @ W1 + b1) ----
#pragma unroll
    for (int q = 0; q < 8; q++) {
        f32x4 bb = cB1[fbq + q];
        acc[4*q+0] = bb.x; acc[4*q+1] = bb.y; acc[4*q+2] = bb.z; acc[4*q+3] = bb.w;
    }
    {
        f32x4 wreg[8];
#pragma unroll
        for (int q = 0; q < 8; q++) wreg[q] = cW1[fbq + q];
#pragma unroll 4
        for (int k = 0; k < 128; k++) {
            int kn = (k < 127) ? (k + 1) : 127;
            f32x4 wn[8];
#pragma unroll
            for (int q = 0; q < 8; q++) wn[q] = cW1[kn * 32 + fbq + q];
            float zv = zT[k * 65 + lane];
#pragma unroll
            for (int q = 0; q < 8; q++) {
                acc[4*q+0] = fmaf(zv, wreg[q].x, acc[4*q+0]);
                acc[4*q+1] = fmaf(zv, wreg[q].y, acc[4*q+1]);
                acc[4*q+2] = fmaf(zv, wreg[q].z, acc[4*q+2]);
                acc[4*q+3] = fmaf(zv, wreg[q].w, acc[4*q+3]);
            }
#pragma unroll
            for (int q = 0; q < 8; q++) wreg[q] = wn[q];
        }
    }
    __syncthreads();   // everyone done reading z
    // write h1 (relu) into same LDS: row = feature, conflict-free
#pragma unroll
    for (int j = 0; j < 32; j++)
        zT[(fbq * 4 + j) * 65 + lane] = fmaxf(acc[j], 0.f);
    __syncthreads();

    // ---- GEMM2: z2 = h1 @ W2 + b2 ----
#pragma unroll
    for (int q = 0; q < 8; q++) {
        f32x4 bb = cB2[fbq + q];
        acc[4*q+0] = bb.x; acc[4*q+1] = bb.y; acc[4*q+2] = bb.z; acc[4*q+3] = bb.w;
    }
    {
        f32x4 wreg[8];
#pragma unroll
        for (int q = 0; q < 8; q++) wreg[q] = cW2[fbq + q];
#pragma unroll 4
        for (int k = 0; k < 128; k++) {
            int kn = (k < 127) ? (k + 1) : 127;
            f32x4 wn[8];
#pragma unroll
            for (int q = 0; q < 8; q++) wn[q] = cW2[kn * 32 + fbq + q];
            float hv = zT[k * 65 + lane];
#pragma unroll
            for (int q = 0; q < 8; q++) {
                acc[4*q+0] = fmaf(hv, wreg[q].x, acc[4*q+0]);
                acc[4*q+1] = fmaf(hv, wreg[q].y, acc[4*q+1]);
                acc[4*q+2] = fmaf(hv, wreg[q].z, acc[4*q+2]);
                acc[4*q+3] = fmaf(hv, wreg[q].w, acc[4*q+3]);
            }
#pragma unroll
            for (int q = 0; q < 8; q++) wreg[q] = wn[q];
        }
    }
    __syncthreads();   // everyone done reading h1
    // park result in LDS for coalesced transpose-out
#pragma unroll
    for (int j = 0; j < 32; j++)
        zT[(fbq * 4 + j) * 65 + lane] = acc[j];
    __syncthreads();
    for (int i = t; i < 64 * 128; i += 256) {
        int n = i >> 7, k = i & 127;
        int gn = base + n;
        if (gn < N_NODES) z2[(size_t)gn * HIDDEN + k] = zT[k * 65 + n];
    }
}

// ---------------- per-feature stats (sum, sumsq) over nodes ----------------
#define STATS_NB 256
__global__ __launch_bounds__(256) void stats_kernel(const float* __restrict__ z2,
                                                    float* __restrict__ stats) {
    __shared__ float red[4][4][64];   // [wave][quantity][lane]
    int t = threadIdx.x, lane = t & 63, w = t >> 6;
    float sl = 0.f, sql = 0.f, sh = 0.f, sqh = 0.f;
    for (int n = blockIdx.x * 4 + w; n < N_NODES; n += STATS_NB * 4) {
        float a = z2[n * HIDDEN + lane];
        float b = z2[n * HIDDEN + 64 + lane];
        sl += a; sql = fmaf(a, a, sql);
        sh += b; sqh = fmaf(b, b, sqh);
    }
    red[w][0][lane] = sl;
    red[w][1][lane] = sql;
    red[w][2][lane] = sh;
    red[w][3][lane] = sqh;
    __syncthreads();
    if (t < 64) {
        unsafeAtomicAdd(&stats[t],
            red[0][0][t] + red[1][0][t] + red[2][0][t] + red[3][0][t]);
    } else if (t < 128) {
        int l = t - 64;
        unsafeAtomicAdd(&stats[64 + l],
            red[0][2][l] + red[1][2][l] + red[2][2][l] + red[3][2][l]);
    } else if (t < 192) {
        int l = t - 128;
        unsafeAtomicAdd(&stats[128 + l],
            red[0][1][l] + red[1][1][l] + red[2][1][l] + red[3][1][l]);
    } else {
        int l = t - 192;
        unsafeAtomicAdd(&stats[192 + l],
            red[0][3][l] + red[1][3][l] + red[2][3][l] + red[3][3][l]);
    }
}

// ---------------- batchnorm + relu + residual (paired features) ----------------
__global__ __launch_bounds__(256) void bn_kernel(
    const float* __restrict__ z2, const float* __restrict__ stats,
    const float* __restrict__ gamma, const float* __restrict__ beta,
    u32* __restrict__ h16, float* __restrict__ out, int write_out) {
    int idx = blockIdx.x * 256 + threadIdx.x;
    if (idx >= N_NODES * 64) return;
    int n = idx >> 6, l = idx & 63;
    const float inv_n = 1.0f / (float)N_NODES;
    float mu_l = stats[l] * inv_n;
    float mu_h = stats[64 + l] * inv_n;
    float var_l = stats[HIDDEN + l] * inv_n - mu_l * mu_l;
    float var_h = stats[HIDDEN + 64 + l] * inv_n - mu_h * mu_h;
    float inv_l = rsqrtf(var_l + BN_EPS);
    float inv_h = rsqrtf(var_h + BN_EPS);
    float zl = (z2[n * HIDDEN + l]      - mu_l) * inv_l * gamma[l]      + beta[l];
    float zh = (z2[n * HIDDEN + 64 + l] - mu_h) * inv_h * gamma[64 + l] + beta[64 + l];
    zl = fmaxf(zl, 0.f);
    zh = fmaxf(zh, 0.f);
    half2_t hh = as_half2(h16[idx]);
    float hn_l = fmaf(RES_SCALE, (float)hh.x, zl);
    float hn_h = fmaf(RES_SCALE, (float)hh.y, zh);
    h16[idx] = pack_half2(hn_l, hn_h);
    if (write_out) {
        out[n * HIDDEN + l] = hn_l;
        out[n * HIDDEN + 64 + l] = hn_h;
    }
}

extern "C" void kernel_launch(void* const* d_in, const int* in_sizes, int n_in,
                              void* d_out, int out_size, void* d_ws, size_t ws_size,
                              hipStream_t stream) {
    const float* x     = (const float*)d_in[0];
    const int*   ei    = (const int*)d_in[1];
    const float* ea    = (const float*)d_in[2];
    const float* We    = (const float*)d_in[3];
    const float* be    = (const float*)d_in[4];
    const float* W1    = (const float*)d_in[5];
    const float* b1    = (const float*)d_in[6];
    const float* W2    = (const float*)d_in[7];
    const float* b2    = (const float*)d_in[8];
    const float* gamma = (const float*)d_in[9];
    const float* beta  = (const float*)d_in[10];
    float* out = (float*)d_out;

    char* wsp = (char*)d_ws;
    const size_t NH = (size_t)N_NODES * HIDDEN;
    u32*      h16    = (u32*)wsp;      wsp += (size_t)N_NODES * 64 * 4;        // 12.8 MB
    float*    z      = (float*)wsp;    wsp += NH * 4;                          // 25.6 MB
    _Float16* ea_perm= (_Float16*)wsp; wsp += (size_t)N_EDGES * EDGE_DIM * 2;  // 51.2 MB
    float*    stats  = (float*)wsp;    wsp += 256 * 4;
    u32*      deg    = (u32*)wsp;      wsp += (size_t)N_NODES * 4;
    u32*      cursor = (u32*)wsp;      wsp += (size_t)N_NODES * 4;
    int*      ssrc   = (int*)wsp;      wsp += (size_t)N_EDGES * 4;
    u32*      off    = (u32*)wsp;      wsp += (size_t)(N_NODES + 1) * 4;
    u32*      bsum   = (u32*)wsp;      wsp += (size_t)SCAN_NB * 4;
    u32*      bbase  = (u32*)wsp;      wsp += (size_t)SCAN_NB * 4;

    const int p_blocks  = (N_NODES * 64 + 255) / 256;       // 12500
    const int e_blocks  = (N_EDGES + 255) / 256;            // 3125
    const int m_blocks  = (N_NODES + 63) / 64;              // 782

    // CSR build (once per call)
    init_kernel<<<p_blocks, 256, 0, stream>>>(x, h16, deg);
    hist_kernel<<<e_blocks, 256, 0, stream>>>(ei, deg);
    scan1_kernel<<<SCAN_NB, 256, 0, stream>>>(deg, bsum);
    scan2_kernel<<<1, 256, 0, stream>>>(bsum, bbase, off);
    scan3_kernel<<<SCAN_NB, 256, 0, stream>>>(deg, bbase, off, cursor);
    scatter_kernel<<<e_blocks, 256, 0, stream>>>(ei, cursor, ssrc, ea, ea_perm);

    for (int l = 0; l < NUM_LAYERS; l++) {
        agg_perm_kernel<<<4096, 256, 0, stream>>>(
            h16, ea_perm, ssrc, off,
            We + (size_t)l * EDGE_DIM * HIDDEN, be + (size_t)l * HIDDEN, z);
        fused_mlp_kernel<<<m_blocks, 256, 0, stream>>>(
            z, W1 + (size_t)l * HIDDEN * HIDDEN, b1 + (size_t)l * HIDDEN,
            W2 + (size_t)l * HIDDEN * HIDDEN, b2 + (size_t)l * HIDDEN, z);
        zero_stats_kernel<<<1, 256, 0, stream>>>(stats);
        stats_kernel<<<STATS_NB, 256, 0, stream>>>(z, stats);
        bn_kernel<<<p_blocks, 256, 0, stream>>>(
            z, stats, gamma + (size_t)l * HIDDEN, beta + (size_t)l * HIDDEN,
            h16, out, (l == NUM_LAYERS - 1) ? 1 : 0);
    }
}